// Round 12
// baseline (805.175 us; speedup 1.0000x reference)
//
#include <hip/hip_runtime.h>
#include <hip/hip_bf16.h>
#include <stdint.h>

// Problem constants
#define BB   32
#define CIN  128
#define HH   64
#define WW   64
#define COUT 256
#define OHH  62
#define OWW  62
#define PIX_PER_B (OHH*OWW)        // 3844
#define NPIX (BB*PIX_PER_B)        // 123008 = 961 * 128
#define KTOT (9*CIN)               // 1152
#define NKT  36                    // K-tiles of BK=32
#define SLOT 24576                 // A 16KB + X 8KB per K-tile

typedef __bf16 bf16x8 __attribute__((ext_vector_type(8)));
typedef float  f32x4  __attribute__((ext_vector_type(4)));
typedef uint16_t u16x8 __attribute__((ext_vector_type(8)));

__device__ __forceinline__ uint16_t f2bf(float f) {
    uint32_t u = __float_as_uint(f);
    uint32_t r = (u + 0x7FFFu + ((u >> 16) & 1u)) >> 16;
    return (uint16_t)r;
}

__device__ __forceinline__ void gload_lds16(const void* g, void* l) {
    __builtin_amdgcn_global_load_lds(
        (const __attribute__((address_space(1))) uint32_t*)g,
        (__attribute__((address_space(3))) uint32_t*)l, 16, 0, 0);
}

// -------- Prepass 1: NCHW fp32 -> NHWC bf16 ----------------------------------
__global__ void __launch_bounds__(256) to_nhwc(const float* __restrict__ in,
                                               uint16_t* __restrict__ out) {
    int slab = blockIdx.x;            // b*64 + h
    int b = slab >> 6, h = slab & 63;
    int w  = threadIdx.x & 63;
    int cp = threadIdx.x >> 6;        // 0..3
    const float* src = in + (((size_t)b * CIN) * HH + h) * WW + w;
    uint16_t* dst = out + ((size_t)slab * WW + w) * CIN;
    #pragma unroll
    for (int it = 0; it < 4; ++it) {
        int c0 = cp * 32 + it * 8;
        u16x8 v;
        #pragma unroll
        for (int j = 0; j < 8; ++j) v[j] = f2bf(src[(c0 + j) * (HH * WW)]);
        *reinterpret_cast<u16x8*>(dst + c0) = v;
    }
}

// -------- Prepass 2: OIHW fp32 -> bf16 [o][uv*128 + c] -----------------------
__global__ void __launch_bounds__(256) pack_w(const float* __restrict__ w,
                                              uint16_t* __restrict__ out) {
    int idx = blockIdx.x * 256 + threadIdx.x;     // < 256*1152
    int o = idx / KTOT;
    int k = idx - o * KTOT;
    int uv = k >> 7, c = k & 127;
    out[idx] = f2bf(w[(o * CIN + c) * 9 + uv]);
}

// -------- Main: 256x128 tile, 8 waves (4Mx2N, 64x64 each), BK=32 -------------
// r4 geometry + RING-2 LDS (2 x 24KB = 49KB incl. tables) -> 3 blocks/CU,
// 24 waves/CU, 6/SIMD: three INDEPENDENT blocks interleave phases to fill
// the exposed latency that kept MfmaUtil at 32% (no pipe >40% busy at r4).
// Lean phase: {stage(t+1)->other slot; 8 ds_read_b128; setprio(1); 16 MFMA;
// setprio(0); vmcnt(0); ONE barrier}. Ring-2 WAR-safe with one barrier:
// phase t's reads complete before its end-barrier (consumed by MFMA);
// stage(t+1) writes are issued after that barrier. vmcnt(0) cover = own
// reads+MFMA (~700cy > L2 latency).
__global__ void __launch_bounds__(512, 6) conv_k32(
        const uint16_t* __restrict__ Xg,   // NHWC bf16 [32][64][64][128]
        const uint16_t* __restrict__ Wg,   // bf16 [256][1152], k=(uv,c)
        const float*    __restrict__ bias, // [256]
        float*          __restrict__ out)  // NCHW fp32 [32][256][62][62]
{
    __shared__ char lds[2 * SLOT + 1024];
    int* pbase = (int*)(lds + 2 * SLOT);   // [128] NHWC elem off of pixel
    int* obase = pbase + 128;              // [128] out flat base (o=0)

    const int tid  = threadIdx.x;
    const int lane = tid & 63;
    const int wid  = tid >> 6;             // 0..7

    // bijective XCD swizzle: nwg=961, q=120, r=1
    int bid = blockIdx.x;
    int xcd = bid & 7, lid = bid >> 3;
    int nt  = (xcd == 0 ? lid : 121 + (xcd - 1) * 120 + lid);

    if (tid < 128) {
        int n   = nt * 128 + tid;
        int b   = n / PIX_PER_B;
        int rem = n - b * PIX_PER_B;
        int oh  = rem / OWW;
        int ow  = rem - oh * OWW;
        pbase[tid] = ((b * 64 + oh) * 64 + ow) * 128;
        obase[tid] = b * (COUT * PIX_PER_B) + rem;
    }
    __syncthreads();

    // ---- staging geometry (r4): stored chunk tid&3 holds logical chunk
    // (tid&3)^((row>>1)&3), row = tid>>2 ----
    const int cs   = (((tid & 3) ^ ((tid >> 3) & 3)) << 4);
    const int ldst = tid * 16;
    const char* aptr0 = (const char*)Wg + (tid >> 2) * (KTOT * 2) + cs;
    const char* aptr1 = (const char*)Wg + (128 + (tid >> 2)) * (KTOT * 2) + cs;
    const char* xptr  = (const char*)Xg + pbase[tid >> 2] * 2 + cs;

    // ---- fragment ds_read byte offsets (r4 swizzle) ----
    const int wm = wid >> 1, wn = wid & 1;   // 4 M-waves x 2 N-waves
    int aro[4], xro[4];
    #pragma unroll
    for (int mi = 0; mi < 4; ++mi) {
        int row = wm * 64 + mi * 16 + (lane & 15);
        aro[mi] = row * 64 + ((((lane >> 4) ^ ((row >> 1) & 3))) << 4);
    }
    #pragma unroll
    for (int nj = 0; nj < 4; ++nj) {
        int row = wn * 64 + nj * 16 + (lane & 15);
        xro[nj] = 16384 + row * 64 + ((((lane >> 4) ^ ((row >> 1) & 3))) << 4);
    }

    f32x4 acc[4][4] = {};

    // Wg k-offset linear in t (t*64 B); X: (u<<14)|(v<<8)|((t&3)<<6)
    auto stage = [&](int t, char* dst) {
        int uvv = t >> 2;
        int u   = (uvv * 11) >> 5;             // uvv/3 for uvv<9
        int v   = uvv - u * 3;
        int xo  = (u << 14) | (v << 8) | ((t & 3) << 6);
        gload_lds16(aptr0 + t * 64, dst + ldst);
        gload_lds16(aptr1 + t * 64, dst + 8192 + ldst);
        gload_lds16(xptr + xo, dst + 16384 + ldst);
    };

// Phase T reading slot S (compile-time 0/1); STG stages T+1 into slot 1-S.
// VMC: 1=vmcnt(0), 0=none. BAR: trailing barrier.
#define PH(T, S, STG, VMC, BAR) do {                                           \
    if (STG) stage((T) + 1, lds + (1 - (S)) * SLOT);                           \
    const char* _s = lds + (S) * SLOT;                                         \
    bf16x8 af[4], xf[4];                                                       \
    _Pragma("unroll") for (int mi = 0; mi < 4; ++mi)                           \
        af[mi] = *reinterpret_cast<const bf16x8*>(_s + aro[mi]);               \
    _Pragma("unroll") for (int nj = 0; nj < 4; ++nj)                           \
        xf[nj] = *reinterpret_cast<const bf16x8*>(_s + xro[nj]);               \
    __builtin_amdgcn_s_setprio(1);                                             \
    _Pragma("unroll") for (int mi = 0; mi < 4; ++mi)                           \
      _Pragma("unroll") for (int nj = 0; nj < 4; ++nj)                         \
        acc[mi][nj] = __builtin_amdgcn_mfma_f32_16x16x32_bf16(                 \
            af[mi], xf[nj], acc[mi][nj], 0, 0, 0);                             \
    __builtin_amdgcn_s_setprio(0);                                             \
    if (VMC) asm volatile("s_waitcnt vmcnt(0)" ::: "memory");                  \
    if (BAR) __builtin_amdgcn_s_barrier();                                     \
} while (0)

    // ---- prologue: stage K-tile 0 only ----
    stage(0, lds);
    asm volatile("s_waitcnt vmcnt(0)" ::: "memory");
    __builtin_amdgcn_s_barrier();

    // ---- main: 17 pairs (t=0..33), peeled t=34,35 ----
    for (int i = 0; i < 17; ++i) {
        PH(2 * i + 0, 0, 1, 1, 1);
        PH(2 * i + 1, 1, 1, 1, 1);
    }
    PH(34, 0, 1, 1, 1);     // stage(35) -> slot 1
    PH(35, 1, 0, 0, 0);
#undef PH

    // ---- epilogue: C/D col=lane&15 (pixel), row=(lane>>4)*4+reg (o) ----
    #pragma unroll
    for (int mi = 0; mi < 4; ++mi) {
        int o = wm * 64 + mi * 16 + ((lane >> 4) << 2);
        #pragma unroll
        for (int reg = 0; reg < 4; ++reg) {
            float bv = bias[o + reg];
            #pragma unroll
            for (int nj = 0; nj < 4; ++nj) {
                int pl = wn * 64 + nj * 16 + (lane & 15);
                out[obase[pl] + (o + reg) * PIX_PER_B] = acc[mi][nj][reg] + bv;
            }
        }
    }
}

// -------- Fallback (ws too small): naive direct conv -------------------------
__global__ void __launch_bounds__(256) conv_naive(const float* __restrict__ in,
                                                  const float* __restrict__ w,
                                                  const float* __restrict__ bias,
                                                  float* __restrict__ out) {
    long idx = (long)blockIdx.x * 256 + threadIdx.x;
    int t = (int)idx;
    int ow = t % OWW; t /= OWW;
    int oh = t % OHH; t /= OHH;
    int o  = t % COUT;
    int b  = t / COUT;
    float s = bias[o];
    for (int c = 0; c < CIN; ++c)
        for (int u = 0; u < 3; ++u)
            for (int v = 0; v < 3; ++v)
                s += in[((b * CIN + c) * HH + oh + u) * WW + ow + v] *
                     w[((o * CIN + c) * 3 + u) * 3 + v];
    out[idx] = s;
}

extern "C" void kernel_launch(void* const* d_in, const int* in_sizes, int n_in,
                              void* d_out, int out_size, void* d_ws, size_t ws_size,
                              hipStream_t stream) {
    const float* in   = (const float*)d_in[0];
    const float* wt   = (const float*)d_in[1];
    const float* bias = (const float*)d_in[2];
    float* out = (float*)d_out;

    const size_t xg_elems = (size_t)BB * HH * WW * CIN;       // 33.5M bf16
    const size_t wg_elems = (size_t)COUT * KTOT;              // 295K bf16
    const size_t need = (xg_elems + wg_elems) * sizeof(uint16_t);

    if (ws_size < need) {
        long total = (long)BB * COUT * OHH * OWW;
        conv_naive<<<(int)((total + 255) / 256), 256, 0, stream>>>(in, wt, bias, out);
        return;
    }

    uint16_t* Xg = (uint16_t*)d_ws;
    uint16_t* Wg = Xg + xg_elems;

    to_nhwc<<<BB * HH, 256, 0, stream>>>(in, Xg);
    pack_w<<<(COUT * KTOT) / 256, 256, 0, stream>>>(wt, Wg);
    conv_k32<<<NPIX / 128, 512, 0, stream>>>(Xg, Wg, bias, out);
}

// Round 13
// 109.496 us; speedup vs baseline: 7.3535x; 7.3535x over previous
//
#include <hip/hip_runtime.h>
#include <hip/hip_bf16.h>
#include <stdint.h>

// Problem constants
#define BB   32
#define CIN  128
#define HH   64
#define WW   64
#define COUT 256
#define OHH  62
#define OWW  62
#define PIX_PER_B (OHH*OWW)        // 3844
#define NPIX (BB*PIX_PER_B)        // 123008 = 961 * 128
#define KTOT (9*CIN)               // 1152
#define NKT  36                    // K-tiles of BK=32
#define SLOT 24576                 // A 16KB + X 8KB per K-tile

typedef __bf16 bf16x8 __attribute__((ext_vector_type(8)));
typedef float  f32x4  __attribute__((ext_vector_type(4)));
typedef uint16_t u16x8 __attribute__((ext_vector_type(8)));

__device__ __forceinline__ uint16_t f2bf(float f) {
    uint32_t u = __float_as_uint(f);
    uint32_t r = (u + 0x7FFFu + ((u >> 16) & 1u)) >> 16;
    return (uint16_t)r;
}

__device__ __forceinline__ void gload_lds16(const void* g, void* l) {
    __builtin_amdgcn_global_load_lds(
        (const __attribute__((address_space(1))) uint32_t*)g,
        (__attribute__((address_space(3))) uint32_t*)l, 16, 0, 0);
}

// -------- Prepass 1: NCHW fp32 -> NHWC bf16 ----------------------------------
__global__ void __launch_bounds__(256) to_nhwc(const float* __restrict__ in,
                                               uint16_t* __restrict__ out) {
    int slab = blockIdx.x;            // b*64 + h
    int b = slab >> 6, h = slab & 63;
    int w  = threadIdx.x & 63;
    int cp = threadIdx.x >> 6;        // 0..3
    const float* src = in + (((size_t)b * CIN) * HH + h) * WW + w;
    uint16_t* dst = out + ((size_t)slab * WW + w) * CIN;
    #pragma unroll
    for (int it = 0; it < 4; ++it) {
        int c0 = cp * 32 + it * 8;
        u16x8 v;
        #pragma unroll
        for (int j = 0; j < 8; ++j) v[j] = f2bf(src[(c0 + j) * (HH * WW)]);
        *reinterpret_cast<u16x8*>(dst + c0) = v;
    }
}

// -------- Prepass 2: OIHW fp32 -> bf16 [o][uv*128 + c] -----------------------
__global__ void __launch_bounds__(256) pack_w(const float* __restrict__ w,
                                              uint16_t* __restrict__ out) {
    int idx = blockIdx.x * 256 + threadIdx.x;     // < 256*1152
    int o = idx / KTOT;
    int k = idx - o * KTOT;
    int uv = k >> 7, c = k & 127;
    out[idx] = f2bf(w[(o * CIN + c) * 9 + uv]);
}

// -------- Main: 256x128 tile, 8 waves (4Mx2N, 64x64 each), BK=32 -------------
// RING-2 LDS (2 x 24KB = 50KB) + __launch_bounds__(512,4): VGPR compiles to
// ~64 (as r4), so LDS is the residency limit -> 3 blocks/CU, 24 waves/CU.
// Three INDEPENDENT blocks interleave their phases: LDS pipe approaches
// saturation (~105 B/cy of 128) and per-phase latency/sync overhead is
// absorbed by cross-block overlap. (r12 failed ONLY because bounds(512,6)
// crushed VGPR to 40 -> acc spilled to scratch: 3.5GB HBM traffic.)
// Lean phase: {stage(t+1)->other slot; 8 ds_read_b128; setprio(1); 16 MFMA;
// setprio(0); vmcnt(0); ONE barrier}. Ring-2 WAR-safe: phase t's reads are
// consumed by its MFMA before its end-barrier; stage(t+1) writes issue after.
__global__ void __launch_bounds__(512, 4) conv_k32(
        const uint16_t* __restrict__ Xg,   // NHWC bf16 [32][64][64][128]
        const uint16_t* __restrict__ Wg,   // bf16 [256][1152], k=(uv,c)
        const float*    __restrict__ bias, // [256]
        float*          __restrict__ out)  // NCHW fp32 [32][256][62][62]
{
    __shared__ char lds[2 * SLOT + 1024];
    int* pbase = (int*)(lds + 2 * SLOT);   // [128] NHWC elem off of pixel
    int* obase = pbase + 128;              // [128] out flat base (o=0)

    const int tid  = threadIdx.x;
    const int lane = tid & 63;
    const int wid  = tid >> 6;             // 0..7

    // bijective XCD swizzle: nwg=961, q=120, r=1
    int bid = blockIdx.x;
    int xcd = bid & 7, lid = bid >> 3;
    int nt  = (xcd == 0 ? lid : 121 + (xcd - 1) * 120 + lid);

    if (tid < 128) {
        int n   = nt * 128 + tid;
        int b   = n / PIX_PER_B;
        int rem = n - b * PIX_PER_B;
        int oh  = rem / OWW;
        int ow  = rem - oh * OWW;
        pbase[tid] = ((b * 64 + oh) * 64 + ow) * 128;
        obase[tid] = b * (COUT * PIX_PER_B) + rem;
    }
    __syncthreads();

    // ---- staging geometry (r4): stored chunk tid&3 holds logical chunk
    // (tid&3)^((row>>1)&3), row = tid>>2 ----
    const int cs   = (((tid & 3) ^ ((tid >> 3) & 3)) << 4);
    const int ldst = tid * 16;
    const char* aptr0 = (const char*)Wg + (tid >> 2) * (KTOT * 2) + cs;
    const char* aptr1 = (const char*)Wg + (128 + (tid >> 2)) * (KTOT * 2) + cs;
    const char* xptr  = (const char*)Xg + pbase[tid >> 2] * 2 + cs;

    // ---- fragment ds_read byte offsets (r4 swizzle) ----
    const int wm = wid >> 1, wn = wid & 1;   // 4 M-waves x 2 N-waves
    int aro[4], xro[4];
    #pragma unroll
    for (int mi = 0; mi < 4; ++mi) {
        int row = wm * 64 + mi * 16 + (lane & 15);
        aro[mi] = row * 64 + ((((lane >> 4) ^ ((row >> 1) & 3))) << 4);
    }
    #pragma unroll
    for (int nj = 0; nj < 4; ++nj) {
        int row = wn * 64 + nj * 16 + (lane & 15);
        xro[nj] = 16384 + row * 64 + ((((lane >> 4) ^ ((row >> 1) & 3))) << 4);
    }

    f32x4 acc[4][4] = {};

    // Wg k-offset linear in t (t*64 B); X: (u<<14)|(v<<8)|((t&3)<<6)
    auto stage = [&](int t, char* dst) {
        int uvv = t >> 2;
        int u   = (uvv * 11) >> 5;             // uvv/3 for uvv<9
        int v   = uvv - u * 3;
        int xo  = (u << 14) | (v << 8) | ((t & 3) << 6);
        gload_lds16(aptr0 + t * 64, dst + ldst);
        gload_lds16(aptr1 + t * 64, dst + 8192 + ldst);
        gload_lds16(xptr + xo, dst + 16384 + ldst);
    };

// Phase T reading slot S (compile-time 0/1); STG stages T+1 into slot 1-S.
// VMC: 1=vmcnt(0), 0=none. BAR: trailing barrier.
#define PH(T, S, STG, VMC, BAR) do {                                           \
    if (STG) stage((T) + 1, lds + (1 - (S)) * SLOT);                           \
    const char* _s = lds + (S) * SLOT;                                         \
    bf16x8 af[4], xf[4];                                                       \
    _Pragma("unroll") for (int mi = 0; mi < 4; ++mi)                           \
        af[mi] = *reinterpret_cast<const bf16x8*>(_s + aro[mi]);               \
    _Pragma("unroll") for (int nj = 0; nj < 4; ++nj)                           \
        xf[nj] = *reinterpret_cast<const bf16x8*>(_s + xro[nj]);               \
    __builtin_amdgcn_s_setprio(1);                                             \
    _Pragma("unroll") for (int mi = 0; mi < 4; ++mi)                           \
      _Pragma("unroll") for (int nj = 0; nj < 4; ++nj)                         \
        acc[mi][nj] = __builtin_amdgcn_mfma_f32_16x16x32_bf16(                 \
            af[mi], xf[nj], acc[mi][nj], 0, 0, 0);                             \
    __builtin_amdgcn_s_setprio(0);                                             \
    if (VMC) asm volatile("s_waitcnt vmcnt(0)" ::: "memory");                  \
    if (BAR) __builtin_amdgcn_s_barrier();                                     \
} while (0)

    // ---- prologue: stage K-tile 0 only ----
    stage(0, lds);
    asm volatile("s_waitcnt vmcnt(0)" ::: "memory");
    __builtin_amdgcn_s_barrier();

    // ---- main: 17 pairs (t=0..33), peeled t=34,35 ----
    for (int i = 0; i < 17; ++i) {
        PH(2 * i + 0, 0, 1, 1, 1);
        PH(2 * i + 1, 1, 1, 1, 1);
    }
    PH(34, 0, 1, 1, 1);     // stage(35) -> slot 1
    PH(35, 1, 0, 0, 0);
#undef PH

    // ---- epilogue: C/D col=lane&15 (pixel), row=(lane>>4)*4+reg (o) ----
    #pragma unroll
    for (int mi = 0; mi < 4; ++mi) {
        int o = wm * 64 + mi * 16 + ((lane >> 4) << 2);
        #pragma unroll
        for (int reg = 0; reg < 4; ++reg) {
            float bv = bias[o + reg];
            #pragma unroll
            for (int nj = 0; nj < 4; ++nj) {
                int pl = wn * 64 + nj * 16 + (lane & 15);
                out[obase[pl] + (o + reg) * PIX_PER_B] = acc[mi][nj][reg] + bv;
            }
        }
    }
}

// -------- Fallback (ws too small): naive direct conv -------------------------
__global__ void __launch_bounds__(256) conv_naive(const float* __restrict__ in,
                                                  const float* __restrict__ w,
                                                  const float* __restrict__ bias,
                                                  float* __restrict__ out) {
    long idx = (long)blockIdx.x * 256 + threadIdx.x;
    int t = (int)idx;
    int ow = t % OWW; t /= OWW;
    int oh = t % OHH; t /= OHH;
    int o  = t % COUT;
    int b  = t / COUT;
    float s = bias[o];
    for (int c = 0; c < CIN; ++c)
        for (int u = 0; u < 3; ++u)
            for (int v = 0; v < 3; ++v)
                s += in[((b * CIN + c) * HH + oh + u) * WW + ow + v] *
                     w[((o * CIN + c) * 3 + u) * 3 + v];
    out[idx] = s;
}

extern "C" void kernel_launch(void* const* d_in, const int* in_sizes, int n_in,
                              void* d_out, int out_size, void* d_ws, size_t ws_size,
                              hipStream_t stream) {
    const float* in   = (const float*)d_in[0];
    const float* wt   = (const float*)d_in[1];
    const float* bias = (const float*)d_in[2];
    float* out = (float*)d_out;

    const size_t xg_elems = (size_t)BB * HH * WW * CIN;       // 33.5M bf16
    const size_t wg_elems = (size_t)COUT * KTOT;              // 295K bf16
    const size_t need = (xg_elems + wg_elems) * sizeof(uint16_t);

    if (ws_size < need) {
        long total = (long)BB * COUT * OHH * OWW;
        conv_naive<<<(int)((total + 255) / 256), 256, 0, stream>>>(in, wt, bias, out);
        return;
    }

    uint16_t* Xg = (uint16_t*)d_ws;
    uint16_t* Wg = Xg + xg_elems;

    to_nhwc<<<BB * HH, 256, 0, stream>>>(in, Xg);
    pack_w<<<(COUT * KTOT) / 256, 256, 0, stream>>>(wt, Wg);
    conv_k32<<<NPIX / 128, 512, 0, stream>>>(Xg, Wg, bias, out);
}